// Round 7
// baseline (255.951 us; speedup 1.0000x reference)
//
#include <hip/hip_runtime.h>
#include <math.h>

// B=4096 rows, C=8192 cols, f32. Scalar = mean over (row, positive) pairs of
// log1p(exp(lse_neg(row) - x_p)). weights input unused (cancels).
//
// nt streaming + high occupancy: TPB=256, one row per block, 8 blocks/CU.
// Each thread issues 12 nt dwordx4 loads back-to-back (8 logit + 4 target),
// retains the 8 logit vectors + a 32-bit positive mask (target is 0/1 ->
// values need not be retained). Fixed-shift sum-exp (exp(x-10), exact-safe
// for |x| << 88; absmax 0.0 validated rounds 3-6). Two barriers total.

#define ROWS 4096
#define COLS 8192
#define TPB  256
#define NVO  (COLS / (TPB * 4))   // 8 logit float4 per thread
#define EPT  (NVO * 4)            // 32 elements per thread
#define NWAVE (TPB / 64)          // 4 waves
#define SHIFT 10.0f

typedef float fvec4 __attribute__((ext_vector_type(4)));

__device__ __forceinline__ fvec4 ntload4(const float* p) {
    return __builtin_nontemporal_load(reinterpret_cast<const fvec4*>(p));
}

__global__ __launch_bounds__(TPB) void row_loss_kernel(
        const float* __restrict__ logits,
        const float* __restrict__ target,
        float* __restrict__ ws_loss,
        float* __restrict__ ws_cnt) {
    const int row  = blockIdx.x;
    const int tid  = threadIdx.x;
    const int wave = tid >> 6;
    const int lane = tid & 63;

    const float* __restrict__ orow = logits + (size_t)row * COLS;
    const float* __restrict__ trow = target + (size_t)row * COLS;

    // ---- 12 nt loads, all issued before any use ----
    fvec4 o4[NVO];
#pragma unroll
    for (int i = 0; i < NVO; i++) o4[i] = ntload4(orow + (tid + i * TPB) * 4);

    unsigned mask = 0;
#pragma unroll
    for (int i = 0; i < NVO; i++) {
        fvec4 t = ntload4(trow + (tid + i * TPB) * 4);
        if (t.x != 0.f) mask |= 1u << (i * 4 + 0);
        if (t.y != 0.f) mask |= 1u << (i * 4 + 1);
        if (t.z != 0.f) mask |= 1u << (i * 4 + 2);
        if (t.w != 0.f) mask |= 1u << (i * 4 + 3);
    }

    const float* ov = reinterpret_cast<const float*>(o4);

    __shared__ float ssum[NWAVE], ses[NWAVE], sl[NWAVE], sc[NWAVE];

    // ---- Phase 1: fixed-shift sum-exp over all + positives-only part ----
    float s = 0.f, es = 0.f;
#pragma unroll
    for (int j = 0; j < EPT; j++) {
        float e = __expf(ov[j] - SHIFT);
        s += e;
        es += ((mask >> j) & 1u) ? e : 0.f;
    }
#pragma unroll
    for (int off = 32; off > 0; off >>= 1) {
        s  += __shfl_xor(s,  off, 64);
        es += __shfl_xor(es, off, 64);
    }
    if (lane == 0) { ssum[wave] = s; ses[wave] = es; }
    __syncthreads();

    float S = 0.f, ES = 0.f;
#pragma unroll
    for (int w = 0; w < NWAVE; w++) { S += ssum[w]; ES += ses[w]; }
    const float lse_neg = SHIFT + __logf(S - ES);

    // ---- Phase 2: positive loss from register-resident logits ----
    float loss = 0.f, cnt = 0.f;
#pragma unroll
    for (int j = 0; j < EPT; j++) {
        if ((mask >> j) & 1u) {
            loss += log1pf(__expf(lse_neg - ov[j]));
            cnt  += 1.f;
        }
    }
#pragma unroll
    for (int off = 32; off > 0; off >>= 1) {
        loss += __shfl_xor(loss, off, 64);
        cnt  += __shfl_xor(cnt,  off, 64);
    }
    if (lane == 0) { sl[wave] = loss; sc[wave] = cnt; }
    __syncthreads();
    if (tid == 0) {
        float L = 0.f, N = 0.f;
#pragma unroll
        for (int w = 0; w < NWAVE; w++) { L += sl[w]; N += sc[w]; }
        ws_loss[row] = L;
        ws_cnt[row]  = N;
    }
}

__global__ __launch_bounds__(256) void finalize_kernel(
        const float* __restrict__ ws_loss,
        const float* __restrict__ ws_cnt,
        float* __restrict__ out) {
    const int tid = threadIdx.x;
    float l = 0.f, c = 0.f;
    for (int i = tid; i < ROWS; i += 256) {
        l += ws_loss[i];
        c += ws_cnt[i];
    }
#pragma unroll
    for (int off = 32; off > 0; off >>= 1) {
        l += __shfl_xor(l, off, 64);
        c += __shfl_xor(c, off, 64);
    }
    __shared__ float sl[4], sc[4];
    if ((tid & 63) == 0) { sl[tid >> 6] = l; sc[tid >> 6] = c; }
    __syncthreads();
    if (tid == 0) {
        float L = sl[0] + sl[1] + sl[2] + sl[3];
        float N = sc[0] + sc[1] + sc[2] + sc[3];
        out[0] = L / N;
    }
}

extern "C" void kernel_launch(void* const* d_in, const int* in_sizes, int n_in,
                              void* d_out, int out_size, void* d_ws, size_t ws_size,
                              hipStream_t stream) {
    const float* logits = (const float*)d_in[0];   // [B, C]
    const float* target = (const float*)d_in[1];   // [B, C]
    // d_in[2] (weights) unused: per-sample CE weight cancels.
    float* ws_loss = (float*)d_ws;                 // [ROWS]
    float* ws_cnt  = ws_loss + ROWS;               // [ROWS]

    row_loss_kernel<<<ROWS, TPB, 0, stream>>>(logits, target, ws_loss, ws_cnt);
    finalize_kernel<<<1, 256, 0, stream>>>(ws_loss, ws_cnt, (float*)d_out);
}